// Round 12
// baseline (266.968 us; speedup 1.0000x reference)
//
#include <hip/hip_runtime.h>
#include <hip/hip_bf16.h>
#include <stdint.h>
#include <math.h>

// B=4, S=2048, D=1024 causal self-attention, f32 I/O.
// out = [output (4,2048,1024) | attn_weights (4,2048,2048)] flat f32.
// Pipeline: cvt(f32->bf16) -> fused QKV GEMM (legacy 128x128 core)
// -> causal scores GEMM (64x128, XCD-grouped) -> row softmax (+bf16 P)
// -> P.Vt GEMM (64x128, causal K-truncation).
// R19 (base: verified R18, 266.0us). Two index/grid remaps, no core changes:
//  1) out: Qi = g(qb>>2), g = cohort-balanced bijection {31-v, v+8, 31-v,
//     v-24}. Under round-robin slot dispatch (validated by qkv's XCD map),
//     each CU's 4-block cohort {v,v+8,v+16,v+24} now sums to 62+4 ksteps
//     (was 48..76, +-23% imbalance -> makespan 1.2x ideal).
//  2) softmax: 8192 -> 2048 blocks; block g does rows {r, 2047-r} x 2
//     batches (lengths sum to 2049 = const -> perfect balance; 4x fewer
//     dispatches). Inner row code identical + syncthreads for red[] reuse.

typedef __hip_bfloat16 bf16;
typedef __attribute__((ext_vector_type(8))) short short8;
typedef __attribute__((ext_vector_type(4))) float f32x4;

#define BM 128
#define BN 128
#define BK 64

static constexpr int Bb = 4;
static constexpr int S  = 2048;
static constexpr int D  = 1024;
static constexpr size_t QK_ELEMS = (size_t)Bb * S * D;   // 8388608
static constexpr size_t SS_ELEMS = (size_t)S * S;        // 4194304 per batch
static constexpr size_t W_ELEMS  = (size_t)D * D;        // 1048576

__device__ __forceinline__ void async16(const bf16* g, bf16* l) {
  __builtin_amdgcn_global_load_lds(
      (__attribute__((address_space(1))) const void*)g,
      (__attribute__((address_space(3))) void*)l, 16, 0, 0);
}

// ============== legacy 128x128 core (qkv) — UNCHANGED, verified ===========
template<bool SWAP>
__device__ __forceinline__ void gemm_core(const bf16* __restrict__ A,
                                          const bf16* __restrict__ B,
                                          int ldA, int ldB, int ksteps,
                                          bf16* As, bf16* Bs,
                                          f32x4 acc[4][4])
{
  const int tid  = threadIdx.x;
  const int lane = tid & 63;
  const int wave = tid >> 6;
  const int wm   = (wave & 1) * 64;
  const int wn   = (wave >> 1) * 64;
  const int m16  = lane & 15;
  const int kq   = lane >> 4;
  const int sw   = m16 & 7;          // row-dependent swizzle key

  int r[4], f[4];
  #pragma unroll
  for (int i = 0; i < 4; ++i) {
    const int c = tid + i * 256;
    r[i] = c >> 3;
    f[i] = (((c & 7) ^ (r[i] & 7))) * 8;
  }

  for (int ks = 0; ks < ksteps; ++ks) {
    const int k = ks * BK;
    #pragma unroll
    for (int i = 0; i < 4; ++i)
      async16(A + (size_t)r[i] * ldA + k + f[i], As + ((size_t)tid + i * 256) * 8);
    #pragma unroll
    for (int i = 0; i < 4; ++i)
      async16(B + (size_t)r[i] * ldB + k + f[i], Bs + ((size_t)tid + i * 256) * 8);
    __syncthreads();

    #pragma unroll
    for (int j = 0; j < 2; ++j) {
      const int jc = j * 4 + kq;       // logical K-chunk for this lane
      const int sl = jc ^ sw;          // swizzled LDS slot within row
      short8 af[4], bfr[4];
      #pragma unroll
      for (int i = 0; i < 4; ++i)
        af[i] = *(const short8*)&As[((wm + i * 16 + m16) * 8 + sl) * 8];
      #pragma unroll
      for (int i = 0; i < 4; ++i)
        bfr[i] = *(const short8*)&Bs[((wn + i * 16 + m16) * 8 + sl) * 8];

      #pragma unroll
      for (int mi = 0; mi < 4; ++mi) {
        #pragma unroll
        for (int ni = 0; ni < 4; ++ni) {
          if (SWAP)
            acc[mi][ni] = __builtin_amdgcn_mfma_f32_16x16x32_bf16(
                bfr[ni], af[mi], acc[mi][ni], 0, 0, 0);
          else
            acc[mi][ni] = __builtin_amdgcn_mfma_f32_16x16x32_bf16(
                af[mi], bfr[ni], acc[mi][ni], 0, 0, 0);
        }
      }
    }
    __syncthreads();
  }
}

__device__ __forceinline__ void zero_acc(f32x4 acc[4][4]) {
  #pragma unroll
  for (int mi = 0; mi < 4; ++mi)
    #pragma unroll
    for (int ni = 0; ni < 4; ++ni)
      acc[mi][ni] = (f32x4){0.f, 0.f, 0.f, 0.f};
}

// ============== 64x128 tile core (scores/out) — UNCHANGED (R15) ===========
__device__ __forceinline__ void gemm_core64(const bf16* __restrict__ A,
                                            const bf16* __restrict__ B,
                                            int ldA, int ldB, int ksteps,
                                            bf16* As, bf16* Bs,
                                            f32x4 acc[4][2])
{
  const int tid  = threadIdx.x;
  const int lane = tid & 63;
  const int wave = tid >> 6;       // 0..3
  const int wn   = wave * 32;      // N col block of 32
  const int m16  = lane & 15;
  const int kq   = lane >> 4;
  const int sw   = m16 & 7;

  int ra[2], fa[2], rb[4], fb[4];
  #pragma unroll
  for (int i = 0; i < 2; ++i) {
    const int c = tid + i * 256;   // 0..511 -> A rows 0..63
    ra[i] = c >> 3;
    fa[i] = ((c & 7) ^ (ra[i] & 7)) * 8;
  }
  #pragma unroll
  for (int i = 0; i < 4; ++i) {
    const int c = tid + i * 256;   // 0..1023 -> B rows 0..127
    rb[i] = c >> 3;
    fb[i] = ((c & 7) ^ (rb[i] & 7)) * 8;
  }

  for (int ks = 0; ks < ksteps; ++ks) {
    const int k = ks * BK;
    #pragma unroll
    for (int i = 0; i < 2; ++i)
      async16(A + (size_t)ra[i] * ldA + k + fa[i], As + ((size_t)tid + i * 256) * 8);
    #pragma unroll
    for (int i = 0; i < 4; ++i)
      async16(B + (size_t)rb[i] * ldB + k + fb[i], Bs + ((size_t)tid + i * 256) * 8);
    __syncthreads();

    #pragma unroll
    for (int j = 0; j < 2; ++j) {
      const int jc = j * 4 + kq;
      const int sl = jc ^ sw;
      short8 af[4], bfr[2];
      #pragma unroll
      for (int i = 0; i < 4; ++i)
        af[i] = *(const short8*)&As[((i * 16 + m16) * 8 + sl) * 8];
      #pragma unroll
      for (int i = 0; i < 2; ++i)
        bfr[i] = *(const short8*)&Bs[((wn + i * 16 + m16) * 8 + sl) * 8];

      #pragma unroll
      for (int mi = 0; mi < 4; ++mi)
        #pragma unroll
        for (int ni = 0; ni < 2; ++ni)
          acc[mi][ni] = __builtin_amdgcn_mfma_f32_16x16x32_bf16(
              af[mi], bfr[ni], acc[mi][ni], 0, 0, 0);
    }
    __syncthreads();
  }
}

__device__ __forceinline__ void zero_acc64(f32x4 acc[4][2]) {
  #pragma unroll
  for (int mi = 0; mi < 4; ++mi)
    #pragma unroll
    for (int ni = 0; ni < 2; ++ni)
      acc[mi][ni] = (f32x4){0.f, 0.f, 0.f, 0.f};
}

// ---- Stage 0: f32 -> bf16 conversion of X, Wq, Wk, Wv --------------------
__device__ __forceinline__ unsigned short f2b(float f) {
  __hip_bfloat16 h = __float2bfloat16(f);
  return *(unsigned short*)&h;
}

__global__ __launch_bounds__(256)
void cvt_kernel(const float* __restrict__ X,  const float* __restrict__ Wq,
                const float* __restrict__ Wk, const float* __restrict__ Wv,
                bf16* __restrict__ Xb, bf16* __restrict__ Wqb,
                bf16* __restrict__ Wkb, bf16* __restrict__ Wvb)
{
  const size_t g = ((size_t)blockIdx.x * 256 + threadIdx.x) * 4;
  const float* src; bf16* dst; size_t off;
  if (g < QK_ELEMS) { src = X; dst = Xb; off = g; }
  else {
    const size_t h = g - QK_ELEMS;
    const int w = (int)(h >> 20);
    off = h & (W_ELEMS - 1);
    src = (w == 0) ? Wq : (w == 1) ? Wk : Wv;
    dst = (w == 0) ? Wqb : (w == 1) ? Wkb : Wvb;
  }
  const float4 v = *(const float4*)(src + off);
  uint2 o;
  o.x = (uint32_t)f2b(v.x) | ((uint32_t)f2b(v.y) << 16);
  o.y = (uint32_t)f2b(v.z) | ((uint32_t)f2b(v.w) << 16);
  *(uint2*)((unsigned short*)dst + off) = o;
}

// ---- Stage A: fused QKV (legacy core, (256,4) verified) ------------------
__global__ __launch_bounds__(256, 4)
void qkv_kernel(const bf16* __restrict__ X, const bf16* __restrict__ Wq,
                const bf16* __restrict__ Wk, const bf16* __restrict__ Wv,
                bf16* __restrict__ Q, bf16* __restrict__ Ko,
                bf16* __restrict__ Vt)
{
  __shared__ __align__(16) bf16 As[BM * BK];
  __shared__ __align__(16) bf16 Bs[BN * BK];
  const int L = blockIdx.x;               // 0..1535
  const int x = L & 7;                    // XCD (dispatch round-robin %8)
  const int s = L >> 3;                   // 0..191
  const int nt  = s & 7;
  const int zmt = ((s >> 3) << 3) | x;    // 0..191, fixed XCD per (z,mt)
  const int z   = zmt >> 6;
  const int mt  = zmt & 63;
  const bf16* W = (z == 0) ? Wq : (z == 1) ? Wk : Wv;

  const int lane = threadIdx.x & 63, wave = threadIdx.x >> 6;
  const int wm = (wave & 1) * 64, wn = (wave >> 1) * 64;
  const int col0 = lane & 15, row0 = (lane >> 4) * 4;

  f32x4 acc[4][4];
  zero_acc(acc);
  if (z < 2) {
    gemm_core<false>(X + (size_t)mt * 128 * D, W + (size_t)nt * 128 * D,
                     D, D, D / BK, As, Bs, acc);
    bf16* Out = z ? Ko : Q;
    #pragma unroll
    for (int mi = 0; mi < 4; ++mi)
      #pragma unroll
      for (int ni = 0; ni < 4; ++ni)
        #pragma unroll
        for (int r = 0; r < 4; ++r) {
          const int grow = mt * 128 + wm + mi * 16 + row0 + r;
          const int gcol = nt * 128 + wn + ni * 16 + col0;
          Out[(size_t)grow * D + gcol] = __float2bfloat16(acc[mi][ni][r]);
        }
  } else {
    gemm_core<true>(X + (size_t)mt * 128 * D, W + (size_t)nt * 128 * D,
                    D, D, D / BK, As, Bs, acc);
    const int b = (mt * 128) >> 11;
    #pragma unroll
    for (int mi = 0; mi < 4; ++mi)
      #pragma unroll
      for (int ni = 0; ni < 4; ++ni)
        #pragma unroll
        for (int r = 0; r < 4; ++r) {
          const int ge = nt * 128 + wn + ni * 16 + row0 + r;      // d index
          const int gs = mt * 128 + wm + mi * 16 + col0;          // s global
          const int sl = gs & (S - 1);
          Vt[(size_t)b * D * S + (size_t)ge * S + sl] = __float2bfloat16(acc[mi][ni][r]);
        }
  }
}

// ---- Stage B: Sc = Q K^T / 32, 64x128 tiles, XCD-aware flat grid. --------
__global__ __launch_bounds__(256, 4)
void scores_kernel(const bf16* __restrict__ Q, const bf16* __restrict__ K,
                   float* __restrict__ Sc)
{
  const int L   = blockIdx.x;               // 0..1087
  const int xcd = L & 7;
  const int b   = xcd >> 1;                 // 2 XCDs per batch
  const int t   = (L >> 3) + (xcd & 1) * 136;   // 0..271
  int m = (int)((sqrtf(4.f * (float)t + 1.f) - 1.f) * 0.5f);
  while ((m + 1) * (m + 2) <= t) ++m;
  while (m * (m + 1) > t) --m;
  const int r_ = t - m * (m + 1);           // 0 .. 2m+1
  const int qi = 2 * m + (r_ > m ? 1 : 0);  // 64-row block 0..31
  const int kt = (r_ > m) ? (r_ - (m + 1)) : r_;

  __shared__ __align__(16) bf16 As[64 * BK];
  __shared__ __align__(16) bf16 Bs[128 * BK];

  f32x4 acc[4][2];
  zero_acc64(acc);
  gemm_core64(Q + ((size_t)b * S + qi * 64) * D,
              K + ((size_t)b * S + kt * 128) * D,
              D, D, D / BK, As, Bs, acc);

  const int lane = threadIdx.x & 63, wave = threadIdx.x >> 6;
  const int col0 = lane & 15, row0 = (lane >> 4) * 4;
  float* out = Sc + (size_t)b * SS_ELEMS;
  #pragma unroll
  for (int mi = 0; mi < 4; ++mi)
    #pragma unroll
    for (int ni = 0; ni < 2; ++ni)
      #pragma unroll
      for (int r = 0; r < 4; ++r) {
        const int gq = qi * 64 + mi * 16 + row0 + r;
        const int gk = kt * 128 + wave * 32 + ni * 16 + col0;
        out[(size_t)gq * S + gk] = acc[mi][ni][r] * 0.03125f;
      }
}

// ---- Stage C: causal row softmax in place (f32) + bf16 P copy ------------
// 2048 blocks; block g handles rows {r, 2047-r} in batches {2bh, 2bh+1}
// (causal lengths sum to 2049 = const -> perfectly balanced blocks).
__device__ __forceinline__ float wave_max(float v) {
  #pragma unroll
  for (int o = 32; o > 0; o >>= 1) v = fmaxf(v, __shfl_xor(v, o, 64));
  return v;
}
__device__ __forceinline__ float wave_sum(float v) {
  #pragma unroll
  for (int o = 32; o > 0; o >>= 1) v += __shfl_xor(v, o, 64);
  return v;
}

__global__ __launch_bounds__(256)
void softmax_kernel(float* __restrict__ Attn, bf16* __restrict__ Pb)
{
  const int g  = blockIdx.x;           // 0..2047
  const int bh = g >> 10;              // batch pair 0..1
  const int r  = g & 1023;
  const int t = threadIdx.x;
  const int lane = t & 63, wave = t >> 6;
  __shared__ float red[4];

  #pragma unroll
  for (int it = 0; it < 4; ++it) {
    const int b = bh * 2 + (it >> 1);
    const int i = (it & 1) ? (S - 1 - r) : r;
    float* s = Attn + (size_t)b * SS_ELEMS + (size_t)i * S;
    bf16* p  = Pb   + (size_t)b * SS_ELEMS + (size_t)i * S;

    float4 v[2];
    #pragma unroll
    for (int u = 0; u < 2; ++u) {
      const int base = (t + u * 256) * 4;
      if (base + 3 <= i) {
        v[u] = *(const float4*)(s + base);
      } else if (base > i) {
        v[u] = make_float4(-INFINITY, -INFINITY, -INFINITY, -INFINITY);
      } else {
        v[u].x = (base + 0 <= i) ? s[base + 0] : -INFINITY;
        v[u].y = (base + 1 <= i) ? s[base + 1] : -INFINITY;
        v[u].z = (base + 2 <= i) ? s[base + 2] : -INFINITY;
        v[u].w = (base + 3 <= i) ? s[base + 3] : -INFINITY;
      }
    }

    float m = -INFINITY;
    #pragma unroll
    for (int u = 0; u < 2; ++u)
      m = fmaxf(m, fmaxf(fmaxf(v[u].x, v[u].y), fmaxf(v[u].z, v[u].w)));
    m = wave_max(m);
    if (lane == 0) red[wave] = m;
    __syncthreads();
    m = fmaxf(fmaxf(red[0], red[1]), fmaxf(red[2], red[3]));
    __syncthreads();

    float sum = 0.f;
    #pragma unroll
    for (int u = 0; u < 2; ++u) {
      v[u].x = __expf(v[u].x - m); sum += v[u].x;
      v[u].y = __expf(v[u].y - m); sum += v[u].y;
      v[u].z = __expf(v[u].z - m); sum += v[u].z;
      v[u].w = __expf(v[u].w - m); sum += v[u].w;
    }
    sum = wave_sum(sum);
    if (lane == 0) red[wave] = sum;
    __syncthreads();
    sum = red[0] + red[1] + red[2] + red[3];
    const float inv = 1.f / sum;         // sum >= 1 (diag term is exp(0))

    const int dt_end = ((i >> 7) + 1) * 128;   // end of diagonal 128-tile
    #pragma unroll
    for (int u = 0; u < 2; ++u) {
      const int base = (t + u * 256) * 4;
      float4 w;
      w.x = v[u].x * inv; w.y = v[u].y * inv;
      w.z = v[u].z * inv; w.w = v[u].w * inv;
      *(float4*)(s + base) = w;          // f32 attn weights (0 above diag)
      if (base < dt_end) {
        ushort4 pk;
        pk.x = f2b(w.x); pk.y = f2b(w.y); pk.z = f2b(w.z); pk.w = f2b(w.w);
        *(ushort4*)((unsigned short*)p + base) = pk;
      }
    }
    __syncthreads();                     // red[] reuse across iterations
  }
}

// ---- Stage D: O = P Vt^T, 64x128 tiles, causal K-truncation. -------------
// 1024 blocks. Qi = g(qb>>2): cohort-balanced bijection so each CU's
// 4-block cohort {v,v+8,v+16,v+24} sums to 62+4 ksteps (constant work).
__global__ __launch_bounds__(256, 4)
void out_kernel(const bf16* __restrict__ P, const bf16* __restrict__ Vt,
                float* __restrict__ O)
{
  const int L = blockIdx.x;               // 0..1023
  const int x = L & 7;                    // XCD
  const int s = L >> 3;                   // 0..127
  const int dt  = s & 7;
  const int qb  = ((s >> 3) << 3) | x;    // 0..127, fixed XCD per (b,Q)
  const int v   = qb >> 2;                // 0..31
  const int Qi  = (v < 8) ? (31 - v) : (v < 16) ? (v + 8)
                : (v < 24) ? (31 - v) : (v - 24);   // cohort-balanced
  const int b   = qb & 3;

  __shared__ __align__(16) bf16 As[64 * BK];
  __shared__ __align__(16) bf16 Bs[128 * BK];

  f32x4 acc[4][2];
  zero_acc64(acc);
  gemm_core64(P + (size_t)b * SS_ELEMS + (size_t)Qi * 64 * S,
              Vt + (size_t)b * D * S + (size_t)dt * 128 * S,
              S, S, Qi + 1, As, Bs, acc);

  const int lane = threadIdx.x & 63, wave = threadIdx.x >> 6;
  const int col0 = lane & 15, row0 = (lane >> 4) * 4;
  #pragma unroll
  for (int mi = 0; mi < 4; ++mi)
    #pragma unroll
    for (int ni = 0; ni < 2; ++ni)
      #pragma unroll
      for (int r = 0; r < 4; ++r) {
        const int gq = Qi * 64 + mi * 16 + row0 + r;
        const int gd = dt * 128 + wave * 32 + ni * 16 + col0;
        O[((size_t)b * S + gq) * D + gd] = acc[mi][ni][r];
      }
}

extern "C" void kernel_launch(void* const* d_in, const int* in_sizes, int n_in,
                              void* d_out, int out_size, void* d_ws, size_t ws_size,
                              hipStream_t stream) {
  const float* X  = (const float*)d_in[0];
  // d_in[1] = causal mask (int32 tril) — applied analytically, not read.
  const float* Wq = (const float*)d_in[2];
  const float* Wk = (const float*)d_in[3];
  const float* Wv = (const float*)d_in[4];

  float* Out  = (float*)d_out;               // (4,2048,1024) f32
  float* Attn = Out + QK_ELEMS;              // (4,2048,2048) f32

  bf16* Q   = (bf16*)d_ws;                   // 16MB
  bf16* K   = Q + QK_ELEMS;                  // 16MB
  bf16* Vt  = K + QK_ELEMS;                  // 16MB
  bf16* Xb  = Vt + QK_ELEMS;                 // 16MB
  bf16* Wqb = Xb + QK_ELEMS;                 // 2MB
  bf16* Wkb = Wqb + W_ELEMS;                 // 2MB
  bf16* Wvb = Wkb + W_ELEMS;                 // 2MB  -> ws total 70MB
  bf16* Pb  = (bf16*)d_ws;                   // 32MB, aliases Q+K (dead by then)

  const int cvt_blocks = (int)((QK_ELEMS + 3 * W_ELEMS) / 4 / 256);
  cvt_kernel<<<cvt_blocks, 256, 0, stream>>>(X, Wq, Wk, Wv, Xb, Wqb, Wkb, Wvb);
  qkv_kernel<<<dim3(1536), 256, 0, stream>>>(Xb, Wqb, Wkb, Wvb, Q, K, Vt);
  scores_kernel<<<dim3(1088), 256, 0, stream>>>(Q, K, Attn);
  softmax_kernel<<<dim3(2048), 256, 0, stream>>>(Attn, Pb);
  out_kernel<<<dim3(1024), 256, 0, stream>>>(Pb, Vt, Out);
}

// Round 13
// 262.657 us; speedup vs baseline: 1.0164x; 1.0164x over previous
//
#include <hip/hip_runtime.h>
#include <hip/hip_bf16.h>
#include <stdint.h>
#include <math.h>

// B=4, S=2048, D=1024 causal self-attention, f32 I/O.
// out = [output (4,2048,1024) | attn_weights (4,2048,2048)] flat f32.
// Pipeline: cvt(f32->bf16) -> fused QKV GEMM (legacy 128x128 core)
// -> causal scores GEMM (64x128, XCD-grouped) -> row softmax (+bf16 P)
// -> P.Vt GEMM (64x128, causal K-truncation).
// R20 = FINAL: exact revert to best-verified R18 (266.0us). R19's two
// balance remaps (out cohort bijection, softmax row-pairing) measured
// neutral (267.0, inside +-3% noise) and are dropped. Verified feature
// set: 128x128 2-barrier core for qkv (4 blocks/CU, XCD-grouped, FETCH
// 178->44MB), 64x128 core for scores/out (doubled grids, +8us vs 128x128),
// scores XCD-flat grid, softmax __expf, heavy-first causal out.
// Session ledger: 8-phase rewrites 0/2 (MfmaUtil DROPPED both times),
// M-trick -7us (launch overhead > 15GF saved), (256,5) bounds -47us
// (VGPR 108->48 spill). 275.5 -> 266.0 total.

typedef __hip_bfloat16 bf16;
typedef __attribute__((ext_vector_type(8))) short short8;
typedef __attribute__((ext_vector_type(4))) float f32x4;

#define BM 128
#define BN 128
#define BK 64

static constexpr int Bb = 4;
static constexpr int S  = 2048;
static constexpr int D  = 1024;
static constexpr size_t QK_ELEMS = (size_t)Bb * S * D;   // 8388608
static constexpr size_t SS_ELEMS = (size_t)S * S;        // 4194304 per batch
static constexpr size_t W_ELEMS  = (size_t)D * D;        // 1048576

__device__ __forceinline__ void async16(const bf16* g, bf16* l) {
  __builtin_amdgcn_global_load_lds(
      (__attribute__((address_space(1))) const void*)g,
      (__attribute__((address_space(3))) void*)l, 16, 0, 0);
}

// ============== legacy 128x128 core (qkv) — verified ======================
template<bool SWAP>
__device__ __forceinline__ void gemm_core(const bf16* __restrict__ A,
                                          const bf16* __restrict__ B,
                                          int ldA, int ldB, int ksteps,
                                          bf16* As, bf16* Bs,
                                          f32x4 acc[4][4])
{
  const int tid  = threadIdx.x;
  const int lane = tid & 63;
  const int wave = tid >> 6;
  const int wm   = (wave & 1) * 64;
  const int wn   = (wave >> 1) * 64;
  const int m16  = lane & 15;
  const int kq   = lane >> 4;
  const int sw   = m16 & 7;          // row-dependent swizzle key

  int r[4], f[4];
  #pragma unroll
  for (int i = 0; i < 4; ++i) {
    const int c = tid + i * 256;
    r[i] = c >> 3;
    f[i] = (((c & 7) ^ (r[i] & 7))) * 8;
  }

  for (int ks = 0; ks < ksteps; ++ks) {
    const int k = ks * BK;
    #pragma unroll
    for (int i = 0; i < 4; ++i)
      async16(A + (size_t)r[i] * ldA + k + f[i], As + ((size_t)tid + i * 256) * 8);
    #pragma unroll
    for (int i = 0; i < 4; ++i)
      async16(B + (size_t)r[i] * ldB + k + f[i], Bs + ((size_t)tid + i * 256) * 8);
    __syncthreads();

    #pragma unroll
    for (int j = 0; j < 2; ++j) {
      const int jc = j * 4 + kq;       // logical K-chunk for this lane
      const int sl = jc ^ sw;          // swizzled LDS slot within row
      short8 af[4], bfr[4];
      #pragma unroll
      for (int i = 0; i < 4; ++i)
        af[i] = *(const short8*)&As[((wm + i * 16 + m16) * 8 + sl) * 8];
      #pragma unroll
      for (int i = 0; i < 4; ++i)
        bfr[i] = *(const short8*)&Bs[((wn + i * 16 + m16) * 8 + sl) * 8];

      #pragma unroll
      for (int mi = 0; mi < 4; ++mi) {
        #pragma unroll
        for (int ni = 0; ni < 4; ++ni) {
          if (SWAP)
            acc[mi][ni] = __builtin_amdgcn_mfma_f32_16x16x32_bf16(
                bfr[ni], af[mi], acc[mi][ni], 0, 0, 0);
          else
            acc[mi][ni] = __builtin_amdgcn_mfma_f32_16x16x32_bf16(
                af[mi], bfr[ni], acc[mi][ni], 0, 0, 0);
        }
      }
    }
    __syncthreads();
  }
}

__device__ __forceinline__ void zero_acc(f32x4 acc[4][4]) {
  #pragma unroll
  for (int mi = 0; mi < 4; ++mi)
    #pragma unroll
    for (int ni = 0; ni < 4; ++ni)
      acc[mi][ni] = (f32x4){0.f, 0.f, 0.f, 0.f};
}

// ============== 64x128 tile core (scores/out) — verified (R15) ============
__device__ __forceinline__ void gemm_core64(const bf16* __restrict__ A,
                                            const bf16* __restrict__ B,
                                            int ldA, int ldB, int ksteps,
                                            bf16* As, bf16* Bs,
                                            f32x4 acc[4][2])
{
  const int tid  = threadIdx.x;
  const int lane = tid & 63;
  const int wave = tid >> 6;       // 0..3
  const int wn   = wave * 32;      // N col block of 32
  const int m16  = lane & 15;
  const int kq   = lane >> 4;
  const int sw   = m16 & 7;

  int ra[2], fa[2], rb[4], fb[4];
  #pragma unroll
  for (int i = 0; i < 2; ++i) {
    const int c = tid + i * 256;   // 0..511 -> A rows 0..63
    ra[i] = c >> 3;
    fa[i] = ((c & 7) ^ (ra[i] & 7)) * 8;
  }
  #pragma unroll
  for (int i = 0; i < 4; ++i) {
    const int c = tid + i * 256;   // 0..1023 -> B rows 0..127
    rb[i] = c >> 3;
    fb[i] = ((c & 7) ^ (rb[i] & 7)) * 8;
  }

  for (int ks = 0; ks < ksteps; ++ks) {
    const int k = ks * BK;
    #pragma unroll
    for (int i = 0; i < 2; ++i)
      async16(A + (size_t)ra[i] * ldA + k + fa[i], As + ((size_t)tid + i * 256) * 8);
    #pragma unroll
    for (int i = 0; i < 4; ++i)
      async16(B + (size_t)rb[i] * ldB + k + fb[i], Bs + ((size_t)tid + i * 256) * 8);
    __syncthreads();

    #pragma unroll
    for (int j = 0; j < 2; ++j) {
      const int jc = j * 4 + kq;
      const int sl = jc ^ sw;
      short8 af[4], bfr[2];
      #pragma unroll
      for (int i = 0; i < 4; ++i)
        af[i] = *(const short8*)&As[((i * 16 + m16) * 8 + sl) * 8];
      #pragma unroll
      for (int i = 0; i < 2; ++i)
        bfr[i] = *(const short8*)&Bs[((wn + i * 16 + m16) * 8 + sl) * 8];

      #pragma unroll
      for (int mi = 0; mi < 4; ++mi)
        #pragma unroll
        for (int ni = 0; ni < 2; ++ni)
          acc[mi][ni] = __builtin_amdgcn_mfma_f32_16x16x32_bf16(
              af[mi], bfr[ni], acc[mi][ni], 0, 0, 0);
    }
    __syncthreads();
  }
}

__device__ __forceinline__ void zero_acc64(f32x4 acc[4][2]) {
  #pragma unroll
  for (int mi = 0; mi < 4; ++mi)
    #pragma unroll
    for (int ni = 0; ni < 2; ++ni)
      acc[mi][ni] = (f32x4){0.f, 0.f, 0.f, 0.f};
}

// ---- Stage 0: f32 -> bf16 conversion of X, Wq, Wk, Wv --------------------
__device__ __forceinline__ unsigned short f2b(float f) {
  __hip_bfloat16 h = __float2bfloat16(f);
  return *(unsigned short*)&h;
}

__global__ __launch_bounds__(256)
void cvt_kernel(const float* __restrict__ X,  const float* __restrict__ Wq,
                const float* __restrict__ Wk, const float* __restrict__ Wv,
                bf16* __restrict__ Xb, bf16* __restrict__ Wqb,
                bf16* __restrict__ Wkb, bf16* __restrict__ Wvb)
{
  const size_t g = ((size_t)blockIdx.x * 256 + threadIdx.x) * 4;
  const float* src; bf16* dst; size_t off;
  if (g < QK_ELEMS) { src = X; dst = Xb; off = g; }
  else {
    const size_t h = g - QK_ELEMS;
    const int w = (int)(h >> 20);
    off = h & (W_ELEMS - 1);
    src = (w == 0) ? Wq : (w == 1) ? Wk : Wv;
    dst = (w == 0) ? Wqb : (w == 1) ? Wkb : Wvb;
  }
  const float4 v = *(const float4*)(src + off);
  uint2 o;
  o.x = (uint32_t)f2b(v.x) | ((uint32_t)f2b(v.y) << 16);
  o.y = (uint32_t)f2b(v.z) | ((uint32_t)f2b(v.w) << 16);
  *(uint2*)((unsigned short*)dst + off) = o;
}

// ---- Stage A: fused QKV (legacy core, (256,4) verified) ------------------
__global__ __launch_bounds__(256, 4)
void qkv_kernel(const bf16* __restrict__ X, const bf16* __restrict__ Wq,
                const bf16* __restrict__ Wk, const bf16* __restrict__ Wv,
                bf16* __restrict__ Q, bf16* __restrict__ Ko,
                bf16* __restrict__ Vt)
{
  __shared__ __align__(16) bf16 As[BM * BK];
  __shared__ __align__(16) bf16 Bs[BN * BK];
  const int L = blockIdx.x;               // 0..1535
  const int x = L & 7;                    // XCD (dispatch round-robin %8)
  const int s = L >> 3;                   // 0..191
  const int nt  = s & 7;
  const int zmt = ((s >> 3) << 3) | x;    // 0..191, fixed XCD per (z,mt)
  const int z   = zmt >> 6;
  const int mt  = zmt & 63;
  const bf16* W = (z == 0) ? Wq : (z == 1) ? Wk : Wv;

  const int lane = threadIdx.x & 63, wave = threadIdx.x >> 6;
  const int wm = (wave & 1) * 64, wn = (wave >> 1) * 64;
  const int col0 = lane & 15, row0 = (lane >> 4) * 4;

  f32x4 acc[4][4];
  zero_acc(acc);
  if (z < 2) {
    gemm_core<false>(X + (size_t)mt * 128 * D, W + (size_t)nt * 128 * D,
                     D, D, D / BK, As, Bs, acc);
    bf16* Out = z ? Ko : Q;
    #pragma unroll
    for (int mi = 0; mi < 4; ++mi)
      #pragma unroll
      for (int ni = 0; ni < 4; ++ni)
        #pragma unroll
        for (int r = 0; r < 4; ++r) {
          const int grow = mt * 128 + wm + mi * 16 + row0 + r;
          const int gcol = nt * 128 + wn + ni * 16 + col0;
          Out[(size_t)grow * D + gcol] = __float2bfloat16(acc[mi][ni][r]);
        }
  } else {
    gemm_core<true>(X + (size_t)mt * 128 * D, W + (size_t)nt * 128 * D,
                    D, D, D / BK, As, Bs, acc);
    const int b = (mt * 128) >> 11;
    #pragma unroll
    for (int mi = 0; mi < 4; ++mi)
      #pragma unroll
      for (int ni = 0; ni < 4; ++ni)
        #pragma unroll
        for (int r = 0; r < 4; ++r) {
          const int ge = nt * 128 + wn + ni * 16 + row0 + r;      // d index
          const int gs = mt * 128 + wm + mi * 16 + col0;          // s global
          const int sl = gs & (S - 1);
          Vt[(size_t)b * D * S + (size_t)ge * S + sl] = __float2bfloat16(acc[mi][ni][r]);
        }
  }
}

// ---- Stage B: Sc = Q K^T / 32, 64x128 tiles, XCD-aware flat grid. --------
// 1088 blocks: xcd=L&7 -> b=xcd>>1, t=(L>>3)+(xcd&1)*136. Each XCD walks
// one batch-half qi-major: consecutive blocks share the Q 64-row panel and
// walk K panels sequentially -> panel reuse inside the XCD's 4MB L2.
__global__ __launch_bounds__(256, 4)
void scores_kernel(const bf16* __restrict__ Q, const bf16* __restrict__ K,
                   float* __restrict__ Sc)
{
  const int L   = blockIdx.x;               // 0..1087
  const int xcd = L & 7;
  const int b   = xcd >> 1;                 // 2 XCDs per batch
  const int t   = (L >> 3) + (xcd & 1) * 136;   // 0..271
  int m = (int)((sqrtf(4.f * (float)t + 1.f) - 1.f) * 0.5f);
  while ((m + 1) * (m + 2) <= t) ++m;
  while (m * (m + 1) > t) --m;
  const int r_ = t - m * (m + 1);           // 0 .. 2m+1
  const int qi = 2 * m + (r_ > m ? 1 : 0);  // 64-row block 0..31
  const int kt = (r_ > m) ? (r_ - (m + 1)) : r_;

  __shared__ __align__(16) bf16 As[64 * BK];
  __shared__ __align__(16) bf16 Bs[128 * BK];

  f32x4 acc[4][2];
  zero_acc64(acc);
  gemm_core64(Q + ((size_t)b * S + qi * 64) * D,
              K + ((size_t)b * S + kt * 128) * D,
              D, D, D / BK, As, Bs, acc);

  const int lane = threadIdx.x & 63, wave = threadIdx.x >> 6;
  const int col0 = lane & 15, row0 = (lane >> 4) * 4;
  float* out = Sc + (size_t)b * SS_ELEMS;
  #pragma unroll
  for (int mi = 0; mi < 4; ++mi)
    #pragma unroll
    for (int ni = 0; ni < 2; ++ni)
      #pragma unroll
      for (int r = 0; r < 4; ++r) {
        const int gq = qi * 64 + mi * 16 + row0 + r;
        const int gk = kt * 128 + wave * 32 + ni * 16 + col0;
        out[(size_t)gq * S + gk] = acc[mi][ni][r] * 0.03125f;
      }
}

// ---- Stage C: causal row softmax in place (f32) + bf16 P copy ------------
__device__ __forceinline__ float wave_max(float v) {
  #pragma unroll
  for (int o = 32; o > 0; o >>= 1) v = fmaxf(v, __shfl_xor(v, o, 64));
  return v;
}
__device__ __forceinline__ float wave_sum(float v) {
  #pragma unroll
  for (int o = 32; o > 0; o >>= 1) v += __shfl_xor(v, o, 64);
  return v;
}

__global__ __launch_bounds__(256)
void softmax_kernel(float* __restrict__ Attn, bf16* __restrict__ Pb)
{
  const int row = blockIdx.x;            // 0..8191
  const int b = row >> 11, i = row & (S - 1);
  float* s = Attn + (size_t)b * SS_ELEMS + (size_t)i * S;
  bf16* p  = Pb   + (size_t)b * SS_ELEMS + (size_t)i * S;
  const int t = threadIdx.x;
  const int lane = t & 63, wave = t >> 6;
  __shared__ float red[4];

  float4 v[2];
  #pragma unroll
  for (int u = 0; u < 2; ++u) {
    const int base = (t + u * 256) * 4;
    if (base + 3 <= i) {
      v[u] = *(const float4*)(s + base);
    } else if (base > i) {
      v[u] = make_float4(-INFINITY, -INFINITY, -INFINITY, -INFINITY);
    } else {
      v[u].x = (base + 0 <= i) ? s[base + 0] : -INFINITY;
      v[u].y = (base + 1 <= i) ? s[base + 1] : -INFINITY;
      v[u].z = (base + 2 <= i) ? s[base + 2] : -INFINITY;
      v[u].w = (base + 3 <= i) ? s[base + 3] : -INFINITY;
    }
  }

  float m = -INFINITY;
  #pragma unroll
  for (int u = 0; u < 2; ++u)
    m = fmaxf(m, fmaxf(fmaxf(v[u].x, v[u].y), fmaxf(v[u].z, v[u].w)));
  m = wave_max(m);
  if (lane == 0) red[wave] = m;
  __syncthreads();
  m = fmaxf(fmaxf(red[0], red[1]), fmaxf(red[2], red[3]));
  __syncthreads();

  float sum = 0.f;
  #pragma unroll
  for (int u = 0; u < 2; ++u) {
    v[u].x = __expf(v[u].x - m); sum += v[u].x;
    v[u].y = __expf(v[u].y - m); sum += v[u].y;
    v[u].z = __expf(v[u].z - m); sum += v[u].z;
    v[u].w = __expf(v[u].w - m); sum += v[u].w;
  }
  sum = wave_sum(sum);
  if (lane == 0) red[wave] = sum;
  __syncthreads();
  sum = red[0] + red[1] + red[2] + red[3];
  const float inv = 1.f / sum;           // sum >= 1 (diag term is exp(0))

  const int dt_end = ((i >> 7) + 1) * 128;   // end of diagonal 128-tile
  #pragma unroll
  for (int u = 0; u < 2; ++u) {
    const int base = (t + u * 256) * 4;
    float4 w;
    w.x = v[u].x * inv; w.y = v[u].y * inv;
    w.z = v[u].z * inv; w.w = v[u].w * inv;
    *(float4*)(s + base) = w;            // f32 attn weights (0 above diag)
    if (base < dt_end) {
      ushort4 pk;
      pk.x = f2b(w.x); pk.y = f2b(w.y); pk.z = f2b(w.z); pk.w = f2b(w.w);
      *(ushort4*)((unsigned short*)p + base) = pk;
    }
  }
}

// ---- Stage D: O = P Vt^T, 64x128 tiles, causal K-truncation. -------------
// 1024 blocks. XCD decode: all 8 dt of one (b,Q) consecutive per XCD
// (P-strip L2 reuse); heavy-Q first. ksteps = Q+1 (BK=64; covers k <= row).
__global__ __launch_bounds__(256, 4)
void out_kernel(const bf16* __restrict__ P, const bf16* __restrict__ Vt,
                float* __restrict__ O)
{
  const int L = blockIdx.x;               // 0..1023
  const int x = L & 7;                    // XCD
  const int s = L >> 3;                   // 0..127
  const int dt  = s & 7;
  const int qb  = ((s >> 3) << 3) | x;    // 0..127, fixed XCD per (b,Q)
  const int Qi  = 31 - (qb >> 2);         // heavy-first 64-row block 0..31
  const int b   = qb & 3;

  __shared__ __align__(16) bf16 As[64 * BK];
  __shared__ __align__(16) bf16 Bs[128 * BK];

  f32x4 acc[4][2];
  zero_acc64(acc);
  gemm_core64(P + (size_t)b * SS_ELEMS + (size_t)Qi * 64 * S,
              Vt + (size_t)b * D * S + (size_t)dt * 128 * S,
              S, S, Qi + 1, As, Bs, acc);

  const int lane = threadIdx.x & 63, wave = threadIdx.x >> 6;
  const int col0 = lane & 15, row0 = (lane >> 4) * 4;
  #pragma unroll
  for (int mi = 0; mi < 4; ++mi)
    #pragma unroll
    for (int ni = 0; ni < 2; ++ni)
      #pragma unroll
      for (int r = 0; r < 4; ++r) {
        const int gq = Qi * 64 + mi * 16 + row0 + r;
        const int gd = dt * 128 + wave * 32 + ni * 16 + col0;
        O[((size_t)b * S + gq) * D + gd] = acc[mi][ni][r];
      }
}

extern "C" void kernel_launch(void* const* d_in, const int* in_sizes, int n_in,
                              void* d_out, int out_size, void* d_ws, size_t ws_size,
                              hipStream_t stream) {
  const float* X  = (const float*)d_in[0];
  // d_in[1] = causal mask (int32 tril) — applied analytically, not read.
  const float* Wq = (const float*)d_in[2];
  const float* Wk = (const float*)d_in[3];
  const float* Wv = (const float*)d_in[4];

  float* Out  = (float*)d_out;               // (4,2048,1024) f32
  float* Attn = Out + QK_ELEMS;              // (4,2048,2048) f32

  bf16* Q   = (bf16*)d_ws;                   // 16MB
  bf16* K   = Q + QK_ELEMS;                  // 16MB
  bf16* Vt  = K + QK_ELEMS;                  // 16MB
  bf16* Xb  = Vt + QK_ELEMS;                 // 16MB
  bf16* Wqb = Xb + QK_ELEMS;                 // 2MB
  bf16* Wkb = Wqb + W_ELEMS;                 // 2MB
  bf16* Wvb = Wkb + W_ELEMS;                 // 2MB  -> ws total 70MB
  bf16* Pb  = (bf16*)d_ws;                   // 32MB, aliases Q+K (dead by then)

  const int cvt_blocks = (int)((QK_ELEMS + 3 * W_ELEMS) / 4 / 256);
  cvt_kernel<<<cvt_blocks, 256, 0, stream>>>(X, Wq, Wk, Wv, Xb, Wqb, Wkb, Wvb);
  qkv_kernel<<<dim3(1536), 256, 0, stream>>>(Xb, Wqb, Wkb, Wvb, Q, K, Vt);
  scores_kernel<<<dim3(1088), 256, 0, stream>>>(Q, K, Attn);
  softmax_kernel<<<dim3(Bb * S), 256, 0, stream>>>(Attn, Pb);
  out_kernel<<<dim3(1024), 256, 0, stream>>>(Pb, Vt, Out);
}